// Round 2
// baseline (544.326 us; speedup 1.0000x reference)
//
#include <hip/hip_runtime.h>
#include <hip/hip_cooperative_groups.h>

namespace cg = cooperative_groups;

// SegmentTree scatter-update + path propagation.
// capacity C = 2^23, n_updates = 2^20, tree = 2C floats (64 MiB).
//
// R9: single fused cooperative kernel. R8 post-mortem: 4 sequential
// dispatches each <40 us summed to 151 us vs ~30 us traffic floor ->
// launch/drain serialization + fbins round-trip dominated. This version:
//   - no binning: scatter values directly into out[C+idx] + 1-bit/leaf
//     dirty bitmap (indices are distinct -> no write races);
//   - merge is barrier-free: each wave owns a 512-leaf region, selects
//     dirty ? out_leaf : tree_leaf, climbs L1..L3 in registers and L4..L9
//     via wave shuffles (dirty bits compressed in a 64-bit ballot mask);
//   - tail (block 0) starts from the 16384 L9 values and finishes to root;
//   - ONE hipLaunchCooperativeKernel with 3 grid.sync()s replaces 4 launches.
// Exact same pairwise sums as reference -> absmax 0.
//
// Grid: 256 blocks x 1024 threads (1 block/CU, 16 waves -> co-resident).
// ws layout:  bitmap uint[C/32]  @ 0        (1 MB)
//             l9flag uchar[16384] @ 1 MB    (16 KB)

typedef unsigned int uint;
typedef unsigned char uchar;
typedef unsigned long long ull;

#define NBLK 256
#define NTHR 1024

// bit j of result = (c bit 2j) | (c bit 2j+1), 64-bit
__device__ __forceinline__ ull pc64(ull c) {
    ull x = (c | (c >> 1)) & 0x5555555555555555ull;
    x = (x | (x >> 1))  & 0x3333333333333333ull;
    x = (x | (x >> 2))  & 0x0F0F0F0F0F0F0F0Full;
    x = (x | (x >> 4))  & 0x00FF00FF00FF00FFull;
    x = (x | (x >> 8))  & 0x0000FFFF0000FFFFull;
    x = (x | (x >> 16)) & 0x00000000FFFFFFFFull;
    return x;
}

__global__ __launch_bounds__(NTHR)
void fused_kernel(const float* __restrict__ tree,
                  const int* __restrict__ idx,
                  const float* __restrict__ val,
                  uint* __restrict__ bitmap,
                  uchar* __restrict__ l9flag,
                  float* __restrict__ out,
                  int C, int nupd) {
    cg::grid_group grid = cg::this_grid();
    const int tid  = threadIdx.x;
    const int b    = blockIdx.x;
    const int gtid = b * NTHR + tid;          // 0 .. 262143

    // ---- P0: clear dirty bitmap (C/32 = 262144 words, 1 per thread) ----
    if (gtid < (C >> 5)) bitmap[gtid] = 0u;
    __threadfence();
    grid.sync();

    // ---- P1: scatter 4 updates per thread into out leaves + bitmap ----
    if (4 * gtid < nupd) {
        int4   j4 = ((const int4*)idx)[gtid];
        float4 v4 = ((const float4*)val)[gtid];
        out[C + j4.x] = v4.x;
        out[C + j4.y] = v4.y;
        out[C + j4.z] = v4.z;
        out[C + j4.w] = v4.w;
        atomicOr(&bitmap[((uint)j4.x) >> 5], 1u << (((uint)j4.x) & 31u));
        atomicOr(&bitmap[((uint)j4.y) >> 5], 1u << (((uint)j4.y) & 31u));
        atomicOr(&bitmap[((uint)j4.z) >> 5], 1u << (((uint)j4.z) & 31u));
        atomicOr(&bitmap[((uint)j4.w) >> 5], 1u << (((uint)j4.w) & 31u));
    }
    __threadfence();
    grid.sync();

    // ---- P2: merge. Wave = 512-leaf region; 16384 regions / 4096 waves
    //          = 4 iterations. No LDS, no barriers. ----
    {
        const int wv   = tid >> 6;
        const int lane = tid & 63;
        #pragma unroll
        for (int it = 0; it < 4; ++it) {
            const int r      = b * 64 + it * 16 + wv;   // region id
            const int gleaf0 = r * 512 + lane * 8;
            uint dm = (uint)((const uchar*)bitmap)[r * 64 + lane];

            float4 ta = *(const float4*)(tree + C + gleaf0);
            float4 tb = *(const float4*)(tree + C + gleaf0 + 4);
            float4 oa = make_float4(0.f, 0.f, 0.f, 0.f), ob = oa;
            if (dm) {   // exec-masked loads: clean 64B lines never fetched
                oa = *(const float4*)(out + C + gleaf0);
                ob = *(const float4*)(out + C + gleaf0 + 4);
            }
            float l0 = (dm &   1u) ? oa.x : ta.x;
            float l1 = (dm &   2u) ? oa.y : ta.y;
            float l2 = (dm &   4u) ? oa.z : ta.z;
            float l3 = (dm &   8u) ? oa.w : ta.w;
            float l4 = (dm &  16u) ? ob.x : tb.x;
            float l5 = (dm &  32u) ? ob.y : tb.y;
            float l6 = (dm &  64u) ? ob.z : tb.z;
            float l7 = (dm & 128u) ? ob.w : tb.w;
            *(float4*)(out + C + gleaf0)     = make_float4(l0, l1, l2, l3);
            *(float4*)(out + C + gleaf0 + 4) = make_float4(l4, l5, l6, l7);

            // L1..L3 in registers
            uint d10 = dm & 3u, d11 = dm & 12u, d12 = dm & 48u, d13 = dm & 192u;
            float4 t1 = *(const float4*)(tree + (C >> 1) + (gleaf0 >> 1));
            float4 v1;
            v1.x = d10 ? l0 + l1 : t1.x;
            v1.y = d11 ? l2 + l3 : t1.y;
            v1.z = d12 ? l4 + l5 : t1.z;
            v1.w = d13 ? l6 + l7 : t1.w;
            *(float4*)(out + (C >> 1) + (gleaf0 >> 1)) = v1;

            float2 t2 = *(const float2*)(tree + (C >> 2) + (gleaf0 >> 2));
            uint d20 = d10 | d11, d21 = d12 | d13;
            float2 v2;
            v2.x = d20 ? v1.x + v1.y : t2.x;
            v2.y = d21 ? v1.z + v1.w : t2.y;
            *(float2*)(out + (C >> 2) + (gleaf0 >> 2)) = v2;

            float t3v = tree[(C >> 3) + (gleaf0 >> 3)];
            uint d3 = d20 | d21;
            float v = d3 ? v2.x + v2.y : t3v;
            out[(C >> 3) + (gleaf0 >> 3)] = v;

            // L4..L9: wave shuffles, dirty bits in ballot mask
            ull m = __ballot(d3 != 0u);
            #pragma unroll
            for (int lvl = 4; lvl <= 9; ++lvl) {
                float a  = __shfl(v, 2 * lane, 64);
                float bb = __shfl(v, 2 * lane + 1, 64);
                m = pc64(m);
                int n = 64 >> (lvl - 3);
                if (lane < n) {
                    int node = (C >> lvl) + (r << (9 - lvl)) + lane;
                    uint dd = (uint)(m >> lane) & 1u;
                    v = dd ? a + bb : tree[node];
                    out[node] = v;
                }
            }
            if (lane == 0) l9flag[r] = (uchar)(m & 1ull);
        }
    }
    __threadfence();
    grid.sync();

    // ---- P3: tail, block 0 only. L10..L13 in registers from the 16384
    //          L9 values, then M=512..16 wave shuffles, 1 barrier, wave 0
    //          finishes M=8..1. ----
    if (b == 0) {
        __shared__ float s16v[16];
        __shared__ uint  s16d[16];
        const int t = tid, w = t >> 6, lane = t & 63;

        const int L9 = C >> 9;                        // 16384
        float s9[16];
        *(float4*)&s9[0]  = *(const float4*)(out + L9 + 16 * t);
        *(float4*)&s9[4]  = *(const float4*)(out + L9 + 16 * t + 4);
        *(float4*)&s9[8]  = *(const float4*)(out + L9 + 16 * t + 8);
        *(float4*)&s9[12] = *(const float4*)(out + L9 + 16 * t + 12);
        uint4 fq = *(const uint4*)(l9flag + 16 * t);  // 16 flag bytes
        uint f[4] = { fq.x, fq.y, fq.z, fq.w };

        const int L10 = C >> 10;                      // 8192
        float4 t10a = *(const float4*)(tree + L10 + 8 * t);
        float4 t10b = *(const float4*)(tree + L10 + 8 * t + 4);
        float t10_[8] = { t10a.x, t10a.y, t10a.z, t10a.w,
                          t10b.x, t10b.y, t10b.z, t10b.w };
        float v10[8]; uint d10_[8];
        #pragma unroll
        for (int k = 0; k < 8; ++k) {
            uint hw = (f[k >> 1] >> ((k & 1) * 16)) & 0xFFFFu;
            d10_[k] = hw != 0u;
            v10[k]  = hw ? s9[2 * k] + s9[2 * k + 1] : t10_[k];
        }
        *(float4*)(out + L10 + 8 * t)     = make_float4(v10[0], v10[1], v10[2], v10[3]);
        *(float4*)(out + L10 + 8 * t + 4) = make_float4(v10[4], v10[5], v10[6], v10[7]);

        const int L11 = C >> 11;                      // 4096
        float4 t11 = *(const float4*)(tree + L11 + 4 * t);
        float t11_[4] = { t11.x, t11.y, t11.z, t11.w };
        float v11[4]; uint d11_[4];
        #pragma unroll
        for (int k = 0; k < 4; ++k) {
            uint d = d10_[2 * k] | d10_[2 * k + 1];
            d11_[k] = d;
            v11[k]  = d ? v10[2 * k] + v10[2 * k + 1] : t11_[k];
        }
        *(float4*)(out + L11 + 4 * t) = make_float4(v11[0], v11[1], v11[2], v11[3]);

        const int L12 = C >> 12;                      // 2048
        float2 t12v = *(const float2*)(tree + L12 + 2 * t);
        uint dA = d11_[0] | d11_[1], dB = d11_[2] | d11_[3];
        float vA = dA ? v11[0] + v11[1] : t12v.x;
        float vB = dB ? v11[2] + v11[3] : t12v.y;
        *(float2*)(out + L12 + 2 * t) = make_float2(vA, vB);

        uint d = dA | dB;
        float v = d ? vA + vB : tree[(C >> 13) + t];  // L13 node 1024+t
        out[(C >> 13) + t] = v;

        ull m = __ballot(d != 0u);
        #pragma unroll
        for (int M = 512; M >= 16; M >>= 1) {
            float a  = __shfl(v, 2 * lane, 64);
            float bb = __shfl(v, 2 * lane + 1, 64);
            m = pc64(m);
            int nw = M >> 4;
            if (lane < nw) {
                int node = M + nw * w + lane;
                uint dd = (uint)(m >> lane) & 1u;
                v = dd ? a + bb : tree[node];
                out[node] = v;
            }
        }
        if (lane == 0) { s16v[w] = v; s16d[w] = (uint)(m & 1ull); }
        __syncthreads();

        if (w == 0) {
            float vv = lane < 16 ? s16v[lane] : 0.f;
            uint dd  = lane < 16 ? s16d[lane] : 0u;
            ull mm = __ballot(dd != 0u);
            #pragma unroll
            for (int M = 8; M >= 1; M >>= 1) {
                float a  = __shfl(vv, 2 * lane, 64);
                float bb = __shfl(vv, 2 * lane + 1, 64);
                mm = pc64(mm);
                if (lane < M) {
                    uint d2 = (uint)(mm >> lane) & 1u;
                    vv = d2 ? a + bb : tree[M + lane];
                    out[M + lane] = vv;
                }
            }
            if (lane == 0) out[0] = tree[0];
        }
    }
}

extern "C" void kernel_launch(void* const* d_in, const int* in_sizes, int n_in,
                              void* d_out, int out_size, void* d_ws, size_t ws_size,
                              hipStream_t stream) {
    const float* tree    = (const float*)d_in[0];
    const int*   indices = (const int*)d_in[1];
    const float* values  = (const float*)d_in[2];
    float* out = (float*)d_out;

    const int two_cap = in_sizes[0];     // 16,777,216
    int C    = two_cap >> 1;             // 8,388,608
    int nupd = in_sizes[1];              // 1,048,576

    uchar* ws = (uchar*)d_ws;
    uint*  bitmap = (uint*)ws;           // 1 MB
    uchar* l9f    = ws + (1 << 20);      // 16 KB

    void* args[8];
    args[0] = (void*)&tree;
    args[1] = (void*)&indices;
    args[2] = (void*)&values;
    args[3] = (void*)&bitmap;
    args[4] = (void*)&l9f;
    args[5] = (void*)&out;
    args[6] = (void*)&C;
    args[7] = (void*)&nupd;

    hipLaunchCooperativeKernel((const void*)fused_kernel,
                               dim3(NBLK), dim3(NTHR), args, 0, stream);
}

// Round 3
// 178.213 us; speedup vs baseline: 3.0543x; 3.0543x over previous
//
#include <hip/hip_runtime.h>

// SegmentTree scatter-update + path propagation.
// capacity C = 2^23, n_updates = 2^20, tree = 2C floats (64 MiB).
//
// R10: multi-launch direct-scatter. R9 post-mortem: fused cooperative kernel
// = 445 us @ 430 GB/s, VALUBusy 1% -- per-wave device-scope fences around
// grid.sync() (buffer_wbl2/buffer_inv) invalidated L2 for every post-sync
// load. Kernel dispatch boundaries do the same flush ONCE in the CP,
// pipelined -> revert to separate launches, keep R9's direct-scatter +
// barrier-free merge (both verified absmax 0):
//   memset:  bitmap = 0 (1 MB, hipMemsetAsync = runtime fillBuffer).
//   scatter: out[C+idx] = val + atomicOr 1-bit/leaf dirty bitmap
//            (indices distinct -> no value races).
//   merge:   wave = 512-leaf region (no LDS, no barriers): select
//            dirty ? out_leaf : tree_leaf, L1..L3 in registers, L4..L9 wave
//            shuffles (dirty bits compressed in ballot mask), write l9flag.
//   tail:    1 block: L10..L13 in registers, M=512..16 shuffles, 1 barrier,
//            wave 0 finishes M=8..1; out[0] = tree[0].
// Exact same pairwise sums as reference -> absmax 0.
//
// ws layout:  bitmap uint[C/32]   @ 0      (1 MB)
//             l9flag uchar[16384] @ 1 MB   (16 KB)

typedef unsigned int uint;
typedef unsigned char uchar;
typedef unsigned long long ull;

// bit j of result = (c bit 2j) | (c bit 2j+1), 64-bit
__device__ __forceinline__ ull pc64(ull c) {
    ull x = (c | (c >> 1)) & 0x5555555555555555ull;
    x = (x | (x >> 1))  & 0x3333333333333333ull;
    x = (x | (x >> 2))  & 0x0F0F0F0F0F0F0F0Full;
    x = (x | (x >> 4))  & 0x00FF00FF00FF00FFull;
    x = (x | (x >> 8))  & 0x0000FFFF0000FFFFull;
    x = (x | (x >> 16)) & 0x00000000FFFFFFFFull;
    return x;
}

__global__ __launch_bounds__(256)
void scatter_kernel(const int* __restrict__ idx,
                    const float* __restrict__ val,
                    uint* __restrict__ bitmap,
                    float* __restrict__ out, int C) {
    const int g = blockIdx.x * 256 + threadIdx.x;   // 0 .. 262143
    int4   j4 = ((const int4*)idx)[g];
    float4 v4 = ((const float4*)val)[g];
    out[C + j4.x] = v4.x;
    out[C + j4.y] = v4.y;
    out[C + j4.z] = v4.z;
    out[C + j4.w] = v4.w;
    atomicOr(&bitmap[((uint)j4.x) >> 5], 1u << (((uint)j4.x) & 31u));
    atomicOr(&bitmap[((uint)j4.y) >> 5], 1u << (((uint)j4.y) & 31u));
    atomicOr(&bitmap[((uint)j4.z) >> 5], 1u << (((uint)j4.z) & 31u));
    atomicOr(&bitmap[((uint)j4.w) >> 5], 1u << (((uint)j4.w) & 31u));
}

// 4096 blocks x 256 threads; wave = one 512-leaf region (r = b*4 + wave).
__global__ __launch_bounds__(256)
void merge_kernel(const float* __restrict__ tree,
                  const uint* __restrict__ bitmap,
                  uchar* __restrict__ l9flag,
                  float* __restrict__ out, int C) {
    const int b    = blockIdx.x;
    const int wv   = threadIdx.x >> 6;
    const int lane = threadIdx.x & 63;
    const int r      = b * 4 + wv;            // region id, 0..16383
    const int gleaf0 = r * 512 + lane * 8;

    uint dm = (uint)((const uchar*)bitmap)[r * 64 + lane];  // 8 leaf bits

    float4 ta = *(const float4*)(tree + C + gleaf0);
    float4 tb = *(const float4*)(tree + C + gleaf0 + 4);
    float4 oa = make_float4(0.f, 0.f, 0.f, 0.f), ob = oa;
    if (dm) {   // exec-masked: clean 64B lines never fetched; poison unread
        oa = *(const float4*)(out + C + gleaf0);
        ob = *(const float4*)(out + C + gleaf0 + 4);
    }
    float l0 = (dm &   1u) ? oa.x : ta.x;
    float l1 = (dm &   2u) ? oa.y : ta.y;
    float l2 = (dm &   4u) ? oa.z : ta.z;
    float l3 = (dm &   8u) ? oa.w : ta.w;
    float l4 = (dm &  16u) ? ob.x : tb.x;
    float l5 = (dm &  32u) ? ob.y : tb.y;
    float l6 = (dm &  64u) ? ob.z : tb.z;
    float l7 = (dm & 128u) ? ob.w : tb.w;
    *(float4*)(out + C + gleaf0)     = make_float4(l0, l1, l2, l3);
    *(float4*)(out + C + gleaf0 + 4) = make_float4(l4, l5, l6, l7);

    // L1..L3 in registers
    uint d10 = dm & 3u, d11 = dm & 12u, d12 = dm & 48u, d13 = dm & 192u;
    float4 t1 = *(const float4*)(tree + (C >> 1) + (gleaf0 >> 1));
    float4 v1;
    v1.x = d10 ? l0 + l1 : t1.x;
    v1.y = d11 ? l2 + l3 : t1.y;
    v1.z = d12 ? l4 + l5 : t1.z;
    v1.w = d13 ? l6 + l7 : t1.w;
    *(float4*)(out + (C >> 1) + (gleaf0 >> 1)) = v1;

    float2 t2 = *(const float2*)(tree + (C >> 2) + (gleaf0 >> 2));
    uint d20 = d10 | d11, d21 = d12 | d13;
    float2 v2;
    v2.x = d20 ? v1.x + v1.y : t2.x;
    v2.y = d21 ? v1.z + v1.w : t2.y;
    *(float2*)(out + (C >> 2) + (gleaf0 >> 2)) = v2;

    float t3v = tree[(C >> 3) + (gleaf0 >> 3)];
    uint d3 = d20 | d21;
    float v = d3 ? v2.x + v2.y : t3v;
    out[(C >> 3) + (gleaf0 >> 3)] = v;

    // L4..L9: wave shuffles, dirty bits carried in ballot mask
    ull m = __ballot(d3 != 0u);
    #pragma unroll
    for (int lvl = 4; lvl <= 9; ++lvl) {
        float a  = __shfl(v, 2 * lane, 64);
        float bb = __shfl(v, 2 * lane + 1, 64);
        m = pc64(m);
        int n = 64 >> (lvl - 3);
        if (lane < n) {
            int node = (C >> lvl) + (r << (9 - lvl)) + lane;
            uint dd = (uint)(m >> lane) & 1u;
            v = dd ? a + bb : tree[node];   // clean nodes carry tree value
            out[node] = v;
        }
    }
    if (lane == 0) l9flag[r] = (uchar)(m & 1ull);
}

// One block, 1024 threads: L10..L23 + out[0]. One barrier.
__global__ __launch_bounds__(1024)
void tail_kernel(const float* __restrict__ tree,
                 const uchar* __restrict__ l9flag,
                 float* __restrict__ out, int C) {
    __shared__ float s16v[16];
    __shared__ uint  s16d[16];
    const int t = threadIdx.x, w = t >> 6, lane = t & 63;

    const int L9 = C >> 9;                        // 16384
    float s9[16];
    *(float4*)&s9[0]  = *(const float4*)(out + L9 + 16 * t);
    *(float4*)&s9[4]  = *(const float4*)(out + L9 + 16 * t + 4);
    *(float4*)&s9[8]  = *(const float4*)(out + L9 + 16 * t + 8);
    *(float4*)&s9[12] = *(const float4*)(out + L9 + 16 * t + 12);
    uint4 fq = *(const uint4*)(l9flag + 16 * t);  // 16 flag bytes
    uint f[4] = { fq.x, fq.y, fq.z, fq.w };

    const int L10 = C >> 10;                      // 8192
    float4 t10a = *(const float4*)(tree + L10 + 8 * t);
    float4 t10b = *(const float4*)(tree + L10 + 8 * t + 4);
    float t10_[8] = { t10a.x, t10a.y, t10a.z, t10a.w,
                      t10b.x, t10b.y, t10b.z, t10b.w };
    float v10[8]; uint d10_[8];
    #pragma unroll
    for (int k = 0; k < 8; ++k) {
        uint hw = (f[k >> 1] >> ((k & 1) * 16)) & 0xFFFFu;
        d10_[k] = hw != 0u;
        v10[k]  = hw ? s9[2 * k] + s9[2 * k + 1] : t10_[k];
    }
    *(float4*)(out + L10 + 8 * t)     = make_float4(v10[0], v10[1], v10[2], v10[3]);
    *(float4*)(out + L10 + 8 * t + 4) = make_float4(v10[4], v10[5], v10[6], v10[7]);

    const int L11 = C >> 11;                      // 4096
    float4 t11 = *(const float4*)(tree + L11 + 4 * t);
    float t11_[4] = { t11.x, t11.y, t11.z, t11.w };
    float v11[4]; uint d11_[4];
    #pragma unroll
    for (int k = 0; k < 4; ++k) {
        uint d = d10_[2 * k] | d10_[2 * k + 1];
        d11_[k] = d;
        v11[k]  = d ? v10[2 * k] + v10[2 * k + 1] : t11_[k];
    }
    *(float4*)(out + L11 + 4 * t) = make_float4(v11[0], v11[1], v11[2], v11[3]);

    const int L12 = C >> 12;                      // 2048
    float2 t12v = *(const float2*)(tree + L12 + 2 * t);
    uint dA = d11_[0] | d11_[1], dB = d11_[2] | d11_[3];
    float vA = dA ? v11[0] + v11[1] : t12v.x;
    float vB = dB ? v11[2] + v11[3] : t12v.y;
    *(float2*)(out + L12 + 2 * t) = make_float2(vA, vB);

    uint d = dA | dB;
    float v = d ? vA + vB : tree[(C >> 13) + t];  // L13 node 1024+t
    out[(C >> 13) + t] = v;

    ull m = __ballot(d != 0u);
    #pragma unroll
    for (int M = 512; M >= 16; M >>= 1) {
        float a  = __shfl(v, 2 * lane, 64);
        float bb = __shfl(v, 2 * lane + 1, 64);
        m = pc64(m);
        int nw = M >> 4;
        if (lane < nw) {
            int node = M + nw * w + lane;
            uint dd = (uint)(m >> lane) & 1u;
            v = dd ? a + bb : tree[node];
            out[node] = v;
        }
    }
    if (lane == 0) { s16v[w] = v; s16d[w] = (uint)(m & 1ull); }
    __syncthreads();

    if (w == 0) {
        float vv = lane < 16 ? s16v[lane] : 0.f;
        uint dd  = lane < 16 ? s16d[lane] : 0u;
        ull mm = __ballot(dd != 0u);
        #pragma unroll
        for (int M = 8; M >= 1; M >>= 1) {
            float a  = __shfl(vv, 2 * lane, 64);
            float bb = __shfl(vv, 2 * lane + 1, 64);
            mm = pc64(mm);
            if (lane < M) {
                uint d2 = (uint)(mm >> lane) & 1u;
                vv = d2 ? a + bb : tree[M + lane];
                out[M + lane] = vv;
            }
        }
        if (lane == 0) out[0] = tree[0];
    }
}

extern "C" void kernel_launch(void* const* d_in, const int* in_sizes, int n_in,
                              void* d_out, int out_size, void* d_ws, size_t ws_size,
                              hipStream_t stream) {
    const float* tree    = (const float*)d_in[0];
    const int*   indices = (const int*)d_in[1];
    const float* values  = (const float*)d_in[2];
    float* out = (float*)d_out;

    const int two_cap = in_sizes[0];     // 16,777,216
    const int C       = two_cap >> 1;    // 8,388,608
    const int nupd    = in_sizes[1];     // 1,048,576

    uchar* ws = (uchar*)d_ws;
    uint*  bitmap = (uint*)ws;           // C/8 bytes = 1 MB
    uchar* l9f    = ws + (1 << 20);      // 16 KB

    hipMemsetAsync(bitmap, 0, (size_t)(C >> 3), stream);
    scatter_kernel<<<nupd / 1024, 256, 0, stream>>>(indices, values,
                                                    bitmap, out, C);
    merge_kernel<<<(C >> 9) / 4, 256, 0, stream>>>(tree, bitmap, l9f, out, C);
    tail_kernel<<<1, 1024, 0, stream>>>(tree, l9f, out, C);
}

// Round 4
// 146.030 us; speedup vs baseline: 3.7275x; 1.2204x over previous
//
#include <hip/hip_runtime.h>

// SegmentTree scatter-update + path propagation.
// capacity C = 2^23, n_updates = 2^20, tree = 2C floats (64 MiB).
//
// R11: bin-to-merge-block. R10 post-mortem: direct scatter = 48 us,
// 1.5 TB/s, 66 MB of scattered dirty-line writes that merge immediately
// overwrote -- scattered-line traffic is ~3x the compact payload. This
// version bins (idx,val) pairs into 1024 bins that EXACTLY match merge
// blocks (8192 leaves each), so merge does zero scattered global reads:
//   memset: cnt[1024] = 0.
//   bin:    256 blocks x 1024 thr: int4 loads, LDS hist(1024) -> one global
//           reserve per non-empty (block,bin) (avg 4-entry = 32 B runs) ->
//           scatter into bins (8 MB compact payload).
//   merge:  1024 blocks x 1024 thr, block = one bin = 8192 leaves:
//           LDS-scatter entries, select dirty ? lds : tree leaves,
//           L1..L3 in registers, L4..L9 wave shuffles (dirty bits in ballot
//           mask), wave 0 finishes L10..L13 in-block, writes l13flag.
//   tail:   1 block: ladder from 1024 L13 values, M=512..16 shuffles,
//           1 barrier, wave 0 does M=8..1; out[0] = tree[0].
// Exact same pairwise sums as reference -> absmax 0.
//
// ws layout:  cnt  uint[1024]        @ 0      (4 KB)
//             l13  uchar[1024]       @ 4096   (1 KB)
//             bins uint2[1024*2048]  @ 32768  (16 MB)

typedef unsigned int uint;
typedef unsigned char uchar;
typedef unsigned long long ull;

#define NBINS 1024
#define BCAP  2048

// bit j of result = (c bit 2j) | (c bit 2j+1), 64-bit
__device__ __forceinline__ ull pc64(ull c) {
    ull x = (c | (c >> 1)) & 0x5555555555555555ull;
    x = (x | (x >> 1))  & 0x3333333333333333ull;
    x = (x | (x >> 2))  & 0x0F0F0F0F0F0F0F0Full;
    x = (x | (x >> 4))  & 0x00FF00FF00FF00FFull;
    x = (x | (x >> 8))  & 0x0000FFFF0000FFFFull;
    x = (x | (x >> 16)) & 0x00000000FFFFFFFFull;
    return x;
}

__global__ __launch_bounds__(1024)
void bin_kernel(const int* __restrict__ idx,
                const float* __restrict__ val,
                uint* __restrict__ cnt,
                uint2* __restrict__ bins) {
    __shared__ uint hist[NBINS];    // histogram, then reused as scatter cursor
    __shared__ uint rbase[NBINS];
    const int tid = threadIdx.x;
    hist[tid] = 0u;
    __syncthreads();

    const int g = blockIdx.x * 1024 + tid;      // int4 units
    int4   j4 = ((const int4*)idx)[g];
    float4 v4 = ((const float4*)val)[g];
    uint  j[4] = { (uint)j4.x, (uint)j4.y, (uint)j4.z, (uint)j4.w };
    float v[4] = { v4.x, v4.y, v4.z, v4.w };

    #pragma unroll
    for (int e = 0; e < 4; ++e) atomicAdd(&hist[j[e] >> 13], 1u);
    __syncthreads();

    uint h = hist[tid];
    rbase[tid] = h ? atomicAdd(&cnt[tid], h) : 0u;
    hist[tid] = 0u;                 // reuse as cursor
    __syncthreads();

    #pragma unroll
    for (int e = 0; e < 4; ++e) {
        uint bin = j[e] >> 13;
        uint r = rbase[bin] + atomicAdd(&hist[bin], 1u);
        if (r < BCAP)
            bins[((size_t)bin << 11) + r] =
                make_uint2(j[e] & 8191u, __float_as_uint(v[e]));
    }
}

// 1024 blocks x 1024 threads; block = one 8192-leaf bin.
__global__ __launch_bounds__(1024)
void merge_kernel(const float* __restrict__ tree,
                  const uint* __restrict__ cnt,
                  const uint2* __restrict__ bins,
                  uchar* __restrict__ l13flag,
                  float* __restrict__ out, int C) {
    __shared__ float slv[8192];     // 32 KB
    __shared__ uchar sfl[8192];     // 8 KB
    __shared__ float s9v[16];
    __shared__ uint  s9d[16];

    const int b    = blockIdx.x;
    const int tid  = threadIdx.x;
    const int wv   = tid >> 6;
    const int lane = tid & 63;

    ((uint2*)sfl)[tid] = make_uint2(0u, 0u);
    __syncthreads();
    uint c = cnt[b];
    if (c > BCAP) c = BCAP;
    const uint2* mybin = bins + ((size_t)b << 11);
    for (uint k = tid; k < c; k += 1024u) {
        uint2 e = mybin[k];
        slv[e.x] = __uint_as_float(e.y);
        sfl[e.x] = 1;
    }
    __syncthreads();

    const int leaf0  = tid * 8;
    const int gleaf0 = b * 8192 + leaf0;

    uint2 fw = *(const uint2*)&sfl[leaf0];
    float4 la = *(const float4*)&slv[leaf0];
    float4 lb = *(const float4*)&slv[leaf0 + 4];
    float4 ta = *(const float4*)(tree + C + gleaf0);
    float4 tb = *(const float4*)(tree + C + gleaf0 + 4);

    float l0 = (fw.x & 0x000000FFu) ? la.x : ta.x;
    float l1 = (fw.x & 0x0000FF00u) ? la.y : ta.y;
    float l2 = (fw.x & 0x00FF0000u) ? la.z : ta.z;
    float l3 = (fw.x & 0xFF000000u) ? la.w : ta.w;
    float l4 = (fw.y & 0x000000FFu) ? lb.x : tb.x;
    float l5 = (fw.y & 0x0000FF00u) ? lb.y : tb.y;
    float l6 = (fw.y & 0x00FF0000u) ? lb.z : tb.z;
    float l7 = (fw.y & 0xFF000000u) ? lb.w : tb.w;

    *(float4*)(out + C + gleaf0)     = make_float4(l0, l1, l2, l3);
    *(float4*)(out + C + gleaf0 + 4) = make_float4(l4, l5, l6, l7);

    // ---- L1..L3 in registers ----
    uint d10 = (fw.x & 0x0000FFFFu) != 0u;
    uint d11 = (fw.x & 0xFFFF0000u) != 0u;
    uint d12 = (fw.y & 0x0000FFFFu) != 0u;
    uint d13 = (fw.y & 0xFFFF0000u) != 0u;
    float4 t1 = *(const float4*)(tree + (C >> 1) + (gleaf0 >> 1));
    float4 v1;
    v1.x = d10 ? l0 + l1 : t1.x;
    v1.y = d11 ? l2 + l3 : t1.y;
    v1.z = d12 ? l4 + l5 : t1.z;
    v1.w = d13 ? l6 + l7 : t1.w;
    *(float4*)(out + (C >> 1) + (gleaf0 >> 1)) = v1;

    float2 t2 = *(const float2*)(tree + (C >> 2) + (gleaf0 >> 2));
    uint d20 = d10 | d11, d21 = d12 | d13;
    float2 v2;
    v2.x = d20 ? v1.x + v1.y : t2.x;
    v2.y = d21 ? v1.z + v1.w : t2.y;
    *(float2*)(out + (C >> 2) + (gleaf0 >> 2)) = v2;

    float t3v = tree[(C >> 3) + (gleaf0 >> 3)];
    uint d3 = d20 | d21;
    float v = d3 ? v2.x + v2.y : t3v;
    out[(C >> 3) + (gleaf0 >> 3)] = v;

    // ---- L4..L9: wave shuffles, dirty bits carried in ballot mask ----
    const int r = b * 16 + wv;          // 512-leaf region id
    ull m = __ballot(d3 != 0u);
    #pragma unroll
    for (int lvl = 4; lvl <= 9; ++lvl) {
        float a  = __shfl(v, 2 * lane, 64);
        float bb = __shfl(v, 2 * lane + 1, 64);
        m = pc64(m);
        int n = 64 >> (lvl - 3);
        if (lane < n) {
            int node = (C >> lvl) + (r << (9 - lvl)) + lane;
            uint dd = (uint)(m >> lane) & 1u;
            v = dd ? a + bb : tree[node];   // clean nodes carry tree value
            out[node] = v;
        }
    }
    if (lane == 0) { s9v[wv] = v; s9d[wv] = (uint)(m & 1ull); }
    __syncthreads();

    // ---- L10..L13: wave 0 finishes the block's 16 L9 values ----
    if (wv == 0) {
        float vv = lane < 16 ? s9v[lane] : 0.f;
        uint dd  = lane < 16 ? s9d[lane] : 0u;
        ull mm = __ballot(dd != 0u);
        #pragma unroll
        for (int lvl = 10; lvl <= 13; ++lvl) {
            float a  = __shfl(vv, 2 * lane, 64);
            float bb = __shfl(vv, 2 * lane + 1, 64);
            mm = pc64(mm);
            int n = 1 << (13 - lvl);        // 8,4,2,1
            if (lane < n) {
                int node = (C >> lvl) + (b << (13 - lvl)) + lane;
                uint d2 = (uint)(mm >> lane) & 1u;
                vv = d2 ? a + bb : tree[node];
                out[node] = vv;
            }
        }
        if (lane == 0) l13flag[b] = (uchar)(mm & 1ull);
    }
}

// One block, 1024 threads: ladder from 1024 L13 values to the root.
__global__ __launch_bounds__(1024)
void tail_kernel(const float* __restrict__ tree,
                 const uchar* __restrict__ l13flag,
                 float* __restrict__ out) {
    __shared__ float s16v[16];
    __shared__ uint  s16d[16];
    const int t = threadIdx.x, w = t >> 6, lane = t & 63;

    float v = out[1024 + t];            // final L13 value (merge wrote it)
    uint d = l13flag[t];

    ull m = __ballot(d != 0u);
    #pragma unroll
    for (int M = 512; M >= 16; M >>= 1) {
        float a  = __shfl(v, 2 * lane, 64);
        float bb = __shfl(v, 2 * lane + 1, 64);
        m = pc64(m);
        int nw = M >> 4;
        if (lane < nw) {
            int node = M + nw * w + lane;
            uint dd = (uint)(m >> lane) & 1u;
            v = dd ? a + bb : tree[node];
            out[node] = v;
        }
    }
    if (lane == 0) { s16v[w] = v; s16d[w] = (uint)(m & 1ull); }
    __syncthreads();

    if (w == 0) {
        float vv = lane < 16 ? s16v[lane] : 0.f;
        uint dd  = lane < 16 ? s16d[lane] : 0u;
        ull mm = __ballot(dd != 0u);
        #pragma unroll
        for (int M = 8; M >= 1; M >>= 1) {
            float a  = __shfl(vv, 2 * lane, 64);
            float bb = __shfl(vv, 2 * lane + 1, 64);
            mm = pc64(mm);
            if (lane < M) {
                uint d2 = (uint)(mm >> lane) & 1u;
                vv = d2 ? a + bb : tree[M + lane];
                out[M + lane] = vv;
            }
        }
        if (lane == 0) out[0] = tree[0];
    }
}

extern "C" void kernel_launch(void* const* d_in, const int* in_sizes, int n_in,
                              void* d_out, int out_size, void* d_ws, size_t ws_size,
                              hipStream_t stream) {
    const float* tree    = (const float*)d_in[0];
    const int*   indices = (const int*)d_in[1];
    const float* values  = (const float*)d_in[2];
    float* out = (float*)d_out;

    const int two_cap = in_sizes[0];     // 16,777,216
    const int C       = two_cap >> 1;    // 8,388,608
    const int nupd    = in_sizes[1];     // 1,048,576

    uchar* ws = (uchar*)d_ws;
    uint*  cnt  = (uint*)ws;             // 4 KB
    uchar* l13  = ws + 4096;             // 1 KB
    uint2* bins = (uint2*)(ws + 32768);  // 16 MB

    hipMemsetAsync(cnt, 0, NBINS * sizeof(uint), stream);
    bin_kernel<<<nupd / 4096, 1024, 0, stream>>>(indices, values, cnt, bins);
    merge_kernel<<<C / 8192, 1024, 0, stream>>>(tree, cnt, bins, l13, out, C);
    tail_kernel<<<1, 1024, 0, stream>>>(tree, l13, out);
}